// Round 4
// baseline (182.296 us; speedup 1.0000x reference)
//
#include <hip/hip_runtime.h>
#include <math.h>

// Problem constants (B derived at launch; spatial dims fixed by weight shapes).
#define HH 1024
#define WW 1024
#define N1 262144   // 512*512 per-image level-1 detail size
#define N2 65536    // 256*256
#define N3 16384    // 128*128
#define TILE_W 512                      // px per block horizontally
#define BLOCKS_PER_B ((WW / TILE_W) * (HH / 8))   // 2*128 = 256 partial rows/batch

#define C_INV_SQRT2 0.70710678118654752440f

static __device__ __forceinline__ void haar_fwd(float P, float Q, float R, float S,
                                                float& a, float& h, float& v, float& d) {
    // reference: split along -1 (cols) first, then -2 (rows)
    const float C = C_INV_SQRT2;
    float lo0 = (P + Q) * C, lo1 = (R + S) * C;
    float hi0 = (P - Q) * C, hi1 = (R - S) * C;
    a = (lo0 + lo1) * C; h = (lo0 - lo1) * C;
    v = (hi0 + hi1) * C; d = (hi0 - hi1) * C;
}

static __device__ __forceinline__ void haar_inv(float a, float h, float v, float d,
                                                float& P, float& Q, float& R, float& S) {
    // reference: merge along -2 (rows) first, then -1 (cols)
    const float C = C_INV_SQRT2;
    float elo = (a + h) * C, olo = (a - h) * C;
    float ehi = (v + d) * C, ohi = (v - d) * C;
    P = (elo + ehi) * C; Q = (elo - ehi) * C;
    R = (olo + ohi) * C; S = (olo - ohi) * C;
}

// ---------------------------------------------------------------------------
// Kernel 1: forward DWT + dot-product logit partials, quarter-split.
// Grid: (WW/512, HH/8, B); 256 threads. Thread = 2 rows x 8 cols of one 8x8
// block: k = t>>2 selects the 8x8 block in a 512x8 strip, q = t&3 the row
// pair. 16384 waves total -> 64 waves/CU of work (was 16). Lane q pairs
// (xor 1) form L2, quads (xor 2) form L3. No atomics: one 10-float partial
// row per block. Layout: [0]=approx, [1..3]=lvl3(Wd1), [4..6]=lvl2(Wd2),
// [7..9]=lvl1(Wd3).
// ---------------------------------------------------------------------------
__global__ __launch_bounds__(256, 8) void wa_fwd_dots(
    const float* __restrict__ x,
    const float* __restrict__ Wa,
    const float* __restrict__ Wd1,   // [3*N3, 3] coarsest
    const float* __restrict__ Wd2,   // [3*N2, 3]
    const float* __restrict__ Wd3,   // [3*N1, 3] finest
    float* __restrict__ partial)     // [B * BLOCKS_PER_B, 10]
{
    const int b = blockIdx.z;
    const int t = threadIdx.x;
    const int k = t >> 2;                    // 8x8 block within 512-px strip
    const int q = t & 3;                     // row-pair within the 8x8 block
    const int x0 = blockIdx.x * TILE_W + k * 8;
    const int y0 = blockIdx.y * 8 + q * 2;   // first of this thread's 2 rows

    const float* xb = x + (size_t)b * HH * WW;

    float p[2][8];
    #pragma unroll
    for (int r = 0; r < 2; ++r) {
        const float4* row = (const float4*)(xb + (size_t)(y0 + r) * WW + x0);
        float4 u0 = row[0], u1 = row[1];
        p[r][0] = u0.x; p[r][1] = u0.y; p[r][2] = u0.z; p[r][3] = u0.w;
        p[r][4] = u1.x; p[r][5] = u1.y; p[r][6] = u1.z; p[r][7] = u1.w;
    }

    float acc[10];
    #pragma unroll
    for (int c = 0; c < 10; ++c) acc[c] = 0.f;

    // ---- Level 1: this thread's row of 4 quads. Compute coeffs first (p
    // dies), then dot stream-by-stream to cap register pressure.
    float a1[4], hh[4], vv[4], dd[4];
    #pragma unroll
    for (int j = 0; j < 4; ++j)
        haar_fwd(p[0][2*j], p[0][2*j+1], p[1][2*j], p[1][2*j+1],
                 a1[j], hh[j], vv[j], dd[j]);
    {
        const size_t jj0 = (size_t)(blockIdx.y * 4 + q) * 512 + (size_t)(x0 >> 1);
        const float4* H = (const float4*)(Wd3 + jj0 * 3);                 // 12 floats, 16B-aligned
        const float4* V = (const float4*)(Wd3 + (jj0 + (size_t)N1) * 3);
        const float4* D = (const float4*)(Wd3 + (jj0 + (size_t)2 * N1) * 3);
        #pragma unroll
        for (int s = 0; s < 3; ++s) {   // streams h, v, d
            const float4* W4 = (s == 0) ? H : (s == 1) ? V : D;
            const float*  cf = (s == 0) ? hh : (s == 1) ? vv : dd;
            float w[12];
            #pragma unroll
            for (int u = 0; u < 3; ++u) {
                float4 f = W4[u];
                w[4*u] = f.x; w[4*u+1] = f.y; w[4*u+2] = f.z; w[4*u+3] = f.w;
            }
            #pragma unroll
            for (int j = 0; j < 4; ++j)
                #pragma unroll
                for (int c = 0; c < 3; ++c)
                    acc[7 + c] += cf[j] * w[3*j + c];
        }
    }

    // ---- Level 2: pair lanes (xor 1). Both lanes compute the row
    // redundantly; only the even lane accumulates the dot.
    float o1[4];
    #pragma unroll
    for (int j = 0; j < 4; ++j) o1[j] = __shfl_xor(a1[j], 1);
    const bool odd = (q & 1);
    float top[4], bot[4];
    #pragma unroll
    for (int j = 0; j < 4; ++j) {
        top[j] = odd ? o1[j] : a1[j];
        bot[j] = odd ? a1[j] : o1[j];
    }
    float a2[2], h2[2], v2[2], d2[2];
    #pragma unroll
    for (int j = 0; j < 2; ++j)
        haar_fwd(top[2*j], top[2*j+1], bot[2*j], bot[2*j+1],
                 a2[j], h2[j], v2[j], d2[j]);
    if (!odd) {
        const size_t kk0 = (size_t)(blockIdx.y * 2 + (q >> 1)) * 256 + (size_t)(x0 >> 2);
        const float2* H = (const float2*)(Wd2 + kk0 * 3);                 // 6 floats, 8B-aligned
        const float2* V = (const float2*)(Wd2 + (kk0 + (size_t)N2) * 3);
        const float2* D = (const float2*)(Wd2 + (kk0 + (size_t)2 * N2) * 3);
        float wh[6], wv[6], wd[6];
        #pragma unroll
        for (int u = 0; u < 3; ++u) {
            float2 fh = H[u]; wh[2*u] = fh.x; wh[2*u+1] = fh.y;
            float2 fv = V[u]; wv[2*u] = fv.x; wv[2*u+1] = fv.y;
            float2 fd = D[u]; wd[2*u] = fd.x; wd[2*u+1] = fd.y;
        }
        #pragma unroll
        for (int j = 0; j < 2; ++j)
            #pragma unroll
            for (int c = 0; c < 3; ++c)
                acc[4 + c] += h2[j] * wh[3*j + c] + v2[j] * wv[3*j + c] + d2[j] * wd[3*j + c];
    }

    // ---- Level 3: quad exchange (xor 2). Lane q==0 accumulates.
    float o2[2];
    #pragma unroll
    for (int j = 0; j < 2; ++j) o2[j] = __shfl_xor(a2[j], 2);
    const bool lower = (q >> 1);
    float t3[2], b3[2];
    #pragma unroll
    for (int j = 0; j < 2; ++j) {
        t3[j] = lower ? o2[j] : a2[j];
        b3[j] = lower ? a2[j] : o2[j];
    }
    if (q == 0) {
        float a, h, v, d;
        haar_fwd(t3[0], t3[1], b3[0], b3[1], a, h, v, d);
        const size_t jj = (size_t)blockIdx.y * 128 + (size_t)(x0 >> 3);
        acc[0] += a * Wa[jj];
        const float* wh = Wd1 + jj * 3;
        const float* wv = Wd1 + (jj + (size_t)N3) * 3;
        const float* wd = Wd1 + (jj + (size_t)2 * N3) * 3;
        #pragma unroll
        for (int c = 0; c < 3; ++c)
            acc[1 + c] += h * wh[c] + v * wv[c] + d * wd[c];
    }

    // Block reduction: wave butterfly -> LDS across 4 waves -> partial row.
    #pragma unroll
    for (int c = 0; c < 10; ++c) {
        float s = acc[c];
        #pragma unroll
        for (int off = 32; off > 0; off >>= 1) s += __shfl_down(s, off, 64);
        acc[c] = s;
    }
    __shared__ float red[4][10];
    const int lane = t & 63, wave = t >> 6;
    if (lane == 0) {
        #pragma unroll
        for (int c = 0; c < 10; ++c) red[wave][c] = acc[c];
    }
    __syncthreads();
    if (t < 10) {
        const int blkflat = b * BLOCKS_PER_B + blockIdx.y * (WW / TILE_W) + blockIdx.x;
        partial[(size_t)blkflat * 10 + t] = red[0][t] + red[1][t] + red[2][t] + red[3][t];
    }
}

// ---------------------------------------------------------------------------
// Kernel 2: reduce 256 partial rows per batch, apply biases, sigmoid/softmax.
// Grid: (B); 64 threads. gates: [0]=sigmoid approx, [1..3]=lvl3, [4..6]=lvl2,
// [7..9]=lvl1.
// ---------------------------------------------------------------------------
__global__ __launch_bounds__(64) void wa_gates(
    const float* __restrict__ partial,
    const float* __restrict__ ba,
    const float* __restrict__ bd1,
    const float* __restrict__ bd2,
    const float* __restrict__ bd3,
    float* __restrict__ gates)
{
    const int b = blockIdx.x;
    const int l = threadIdx.x;
    float v[10];
    #pragma unroll
    for (int c = 0; c < 10; ++c) v[c] = 0.f;
    #pragma unroll
    for (int rep = 0; rep < BLOCKS_PER_B / 64; ++rep) {
        const float* row = partial + (size_t)(b * BLOCKS_PER_B + rep * 64 + l) * 10;
        #pragma unroll
        for (int c = 0; c < 10; ++c) v[c] += row[c];
    }
    #pragma unroll
    for (int c = 0; c < 10; ++c) {
        #pragma unroll
        for (int off = 32; off > 0; off >>= 1) v[c] += __shfl_down(v[c], off, 64);
    }
    if (l == 0) {
        float* G = gates + b * 10;
        G[0] = 1.f / (1.f + expf(-(v[0] + ba[0])));
        const float* bds[3] = { bd1, bd2, bd3 };
        #pragma unroll
        for (int lv = 0; lv < 3; ++lv) {
            float l0 = v[1 + 3*lv + 0] + bds[lv][0];
            float l1 = v[1 + 3*lv + 1] + bds[lv][1];
            float l2 = v[1 + 3*lv + 2] + bds[lv][2];
            float m = fmaxf(l0, fmaxf(l1, l2));
            float e0 = expf(l0 - m), e1 = expf(l1 - m), e2 = expf(l2 - m);
            float inv = 1.f / (e0 + e1 + e2);
            G[1 + 3*lv + 0] = e0 * inv;
            G[1 + 3*lv + 1] = e1 * inv;
            G[1 + 3*lv + 2] = e2 * inv;
        }
    }
}

// ---------------------------------------------------------------------------
// Kernel 3: recompute coefficients, gate, inverse-DWT, write. Quarter-split
// like kernel 1: thread = 2 rows x 8 cols; L2/L3 computed redundantly per
// lane-group; each thread inverts only its own two output rows.
// ---------------------------------------------------------------------------
__global__ __launch_bounds__(256, 8) void wa_recon(
    const float* __restrict__ x,
    const float* __restrict__ gates,
    float* __restrict__ out)
{
    const int b = blockIdx.z;
    const int t = threadIdx.x;

    __shared__ float g[10];
    if (t < 10) g[t] = gates[b * 10 + t];
    __syncthreads();

    const int k = t >> 2;
    const int q = t & 3;
    const int x0 = blockIdx.x * TILE_W + k * 8;
    const int y0 = blockIdx.y * 8 + q * 2;

    const float* xb = x + (size_t)b * HH * WW;

    float p[2][8];
    #pragma unroll
    for (int r = 0; r < 2; ++r) {
        const float4* row = (const float4*)(xb + (size_t)(y0 + r) * WW + x0);
        float4 u0 = row[0], u1 = row[1];
        p[r][0] = u0.x; p[r][1] = u0.y; p[r][2] = u0.z; p[r][3] = u0.w;
        p[r][4] = u1.x; p[r][5] = u1.y; p[r][6] = u1.z; p[r][7] = u1.w;
    }

    // Forward, this thread's L1 row of quads.
    float a1[4], h1[4], v1[4], d1[4];
    #pragma unroll
    for (int j = 0; j < 4; ++j)
        haar_fwd(p[0][2*j], p[0][2*j+1], p[1][2*j], p[1][2*j+1],
                 a1[j], h1[j], v1[j], d1[j]);

    // L2, redundant per pair (xor 1).
    float o1[4];
    #pragma unroll
    for (int j = 0; j < 4; ++j) o1[j] = __shfl_xor(a1[j], 1);
    const bool odd = (q & 1);
    float top[4], bot[4];
    #pragma unroll
    for (int j = 0; j < 4; ++j) {
        top[j] = odd ? o1[j] : a1[j];
        bot[j] = odd ? a1[j] : o1[j];
    }
    float a2[2], h2[2], v2[2], d2[2];
    #pragma unroll
    for (int j = 0; j < 2; ++j)
        haar_fwd(top[2*j], top[2*j+1], bot[2*j], bot[2*j+1],
                 a2[j], h2[j], v2[j], d2[j]);

    // L3, redundant per quad (xor 2).
    float o2[2];
    #pragma unroll
    for (int j = 0; j < 2; ++j) o2[j] = __shfl_xor(a2[j], 2);
    const bool lower = (q >> 1);
    float t3[2], b3[2];
    #pragma unroll
    for (int j = 0; j < 2; ++j) {
        t3[j] = lower ? o2[j] : a2[j];
        b3[j] = lower ? a2[j] : o2[j];
    }
    float a3, h3, v3, d3;
    haar_fwd(t3[0], t3[1], b3[0], b3[1], a3, h3, v3, d3);

    // Gate + inverse. L3 inverse -> full r2 quad (redundant, cheap).
    a3 *= g[0];
    float r2[2][2];
    haar_inv(a3, h3 * g[1], v3 * g[2], d3 * g[3],
             r2[0][0], r2[0][1], r2[1][0], r2[1][1]);
    const int i2 = q >> 1;                       // this lane's L2 row
    float r2m0 = r2[i2][0], r2m1 = r2[i2][1];

    // L2 inverse at row i2; keep output row of parity (q&1) -> r1 row q.
    float r1[4];
    {
        float P, Q, R, S;
        haar_inv(r2m0, h2[0] * g[4], v2[0] * g[5], d2[0] * g[6], P, Q, R, S);
        r1[0] = odd ? R : P;  r1[1] = odd ? S : Q;
        haar_inv(r2m1, h2[1] * g[4], v2[1] * g[5], d2[1] * g[6], P, Q, R, S);
        r1[2] = odd ? R : P;  r1[3] = odd ? S : Q;
    }

    // L1 inverse: r1 row q + own h1/v1/d1 -> output rows 2q, 2q+1.
    float r0[2][8];
    #pragma unroll
    for (int j = 0; j < 4; ++j) {
        float P, Q, R, S;
        haar_inv(r1[j], h1[j] * g[7], v1[j] * g[8], d1[j] * g[9], P, Q, R, S);
        r0[0][2*j] = P; r0[0][2*j+1] = Q;
        r0[1][2*j] = R; r0[1][2*j+1] = S;
    }

    float* ob = out + (size_t)b * HH * WW;
    #pragma unroll
    for (int r = 0; r < 2; ++r) {
        float4* row = (float4*)(ob + (size_t)(y0 + r) * WW + x0);
        float4 u0, u1;
        u0.x = r0[r][0]; u0.y = r0[r][1]; u0.z = r0[r][2]; u0.w = r0[r][3];
        u1.x = r0[r][4]; u1.y = r0[r][5]; u1.z = r0[r][6]; u1.w = r0[r][7];
        row[0] = u0; row[1] = u1;
    }
}

extern "C" void kernel_launch(void* const* d_in, const int* in_sizes, int n_in,
                              void* d_out, int out_size, void* d_ws, size_t ws_size,
                              hipStream_t stream) {
    const float* x   = (const float*)d_in[0];
    const float* Wa  = (const float*)d_in[1];
    const float* ba  = (const float*)d_in[2];
    const float* Wd1 = (const float*)d_in[3];
    const float* bd1 = (const float*)d_in[4];
    const float* Wd2 = (const float*)d_in[5];
    const float* bd2 = (const float*)d_in[6];
    const float* Wd3 = (const float*)d_in[7];
    const float* bd3 = (const float*)d_in[8];
    float* out = (float*)d_out;

    const int B = in_sizes[0] / (HH * WW);

    float* partial = (float*)d_ws;                             // [B*256, 10]
    float* gates   = partial + (size_t)B * BLOCKS_PER_B * 10;  // [B, 10]

    dim3 grid(WW / TILE_W, HH / 8, B);
    wa_fwd_dots<<<grid, 256, 0, stream>>>(x, Wa, Wd1, Wd2, Wd3, partial);
    wa_gates<<<B, 64, 0, stream>>>(partial, ba, bd1, bd2, bd3, gates);
    wa_recon<<<grid, 256, 0, stream>>>(x, gates, out);
}

// Round 5
// 155.675 us; speedup vs baseline: 1.1710x; 1.1710x over previous
//
#include <hip/hip_runtime.h>
#include <math.h>

// Problem constants (B derived at launch; spatial dims fixed by weight shapes).
#define HH 1024
#define WW 1024
#define N1 262144   // 512*512 per-image level-1 detail size
#define N2 65536    // 256*256
#define N3 16384    // 128*128
#define NCHUNK 4           // fwd batch chunks; each block handles B/NCHUNK images
#define ROWS_PER_IMG 512   // partial rows per image = 128 strips * 4 waves

#define C_INV_SQRT2 0.70710678118654752440f

static __device__ __forceinline__ void haar_fwd(float P, float Q, float R, float S,
                                                float& a, float& h, float& v, float& d) {
    // reference: split along -1 (cols) first, then -2 (rows)
    const float C = C_INV_SQRT2;
    float lo0 = (P + Q) * C, lo1 = (R + S) * C;
    float hi0 = (P - Q) * C, hi1 = (R - S) * C;
    a = (lo0 + lo1) * C; h = (lo0 - lo1) * C;
    v = (hi0 + hi1) * C; d = (hi0 - hi1) * C;
}

static __device__ __forceinline__ void haar_inv(float a, float h, float v, float d,
                                                float& P, float& Q, float& R, float& S) {
    // reference: merge along -2 (rows) first, then -1 (cols)
    // P=(r0,c0) Q=(r0,c1) R=(r1,c0) S=(r1,c1)
    const float C = C_INV_SQRT2;
    float elo = (a + h) * C, olo = (a - h) * C;
    float ehi = (v + d) * C, ohi = (v - d) * C;
    P = (elo + ehi) * C; Q = (elo - ehi) * C;
    R = (olo + ohi) * C; S = (olo - ohi) * C;
}

// ---------------------------------------------------------------------------
// Kernel 1: forward DWT + logit partials, batch-amortized weights.
// Grid: (128 strips, NCHUNK); 256 threads. Block = one 1024x8 row-strip for
// B/NCHUNK images. Thread t owns pixel cols [4t,4t+4) x 8 rows (column slab):
// every global load is 64 lanes x contiguous 16B = full 1KB lines. L1/L2
// quads are thread-local; L3 pairs via one __shfl_xor(1). Strip weights live
// in registers, reused across the image loop -> weight traffic 201->50 MB.
// partial row layout: [0]=approx, [1..3]=lvl3(Wd1), [4..6]=lvl2(Wd2),
// [7..9]=lvl1(Wd3). One row per (image, strip, wave); no atomics, no memset.
// ---------------------------------------------------------------------------
__global__ __launch_bounds__(256) void wa_fwd_dots(
    const float* __restrict__ x,
    const float* __restrict__ Wa,
    const float* __restrict__ Wd1,   // [3*N3, 3] coarsest
    const float* __restrict__ Wd2,   // [3*N2, 3]
    const float* __restrict__ Wd3,   // [3*N1, 3] finest
    float* __restrict__ partial,     // [B, ROWS_PER_IMG, 10]
    int ipc)                         // images per chunk
{
    const int strip = blockIdx.x;          // [0,128): pixel rows strip*8..+8
    const int chunk = blockIdx.y;
    const int t = threadIdx.x;             // L2-col index; px cols 4t..4t+3
    const int lane = t & 63, wave = t >> 6;

    // ---- strip weights -> registers (once per block, reused ipc times) ----
    // L1 (Wd3): rows strip*4+qr, cols 2t,2t+1; 6 floats per stream per row.
    float w1[3][4][6];
    #pragma unroll
    for (int qr = 0; qr < 4; ++qr) {
        const size_t jj = (size_t)(strip * 4 + qr) * 512 + 2 * t;
        #pragma unroll
        for (int s = 0; s < 3; ++s) {
            const float2* src = (const float2*)(Wd3 + (jj + (size_t)s * N1) * 3); // 8B-aligned
            float2 f0 = src[0], f1 = src[1], f2 = src[2];
            w1[s][qr][0] = f0.x; w1[s][qr][1] = f0.y; w1[s][qr][2] = f1.x;
            w1[s][qr][3] = f1.y; w1[s][qr][4] = f2.x; w1[s][qr][5] = f2.y;
        }
    }
    // L2 (Wd2): rows strip*2+QR, col t; 3 floats per stream.
    float w2[3][2][3];
    #pragma unroll
    for (int QR = 0; QR < 2; ++QR) {
        const size_t jj = (size_t)(strip * 2 + QR) * 256 + t;
        #pragma unroll
        for (int s = 0; s < 3; ++s) {
            const float* src = Wd2 + (jj + (size_t)s * N2) * 3;
            w2[s][QR][0] = src[0]; w2[s][QR][1] = src[1]; w2[s][QR][2] = src[2];
        }
    }
    // L3 (Wd1 + Wa): row strip, col t>>1 — even lanes only.
    float w3[3][3] = {};
    float wa = 0.f;
    if (!(t & 1)) {
        const size_t jj = (size_t)strip * 128 + (t >> 1);
        wa = Wa[jj];
        #pragma unroll
        for (int s = 0; s < 3; ++s) {
            const float* src = Wd1 + (jj + (size_t)s * N3) * 3;
            w3[s][0] = src[0]; w3[s][1] = src[1]; w3[s][2] = src[2];
        }
    }

    // ---- image loop ----
    #pragma unroll 2
    for (int bi = 0; bi < ipc; ++bi) {
        const int b = chunk * ipc + bi;
        const float* xr = x + (size_t)b * HH * WW + (size_t)strip * 8 * WW + 4 * t;

        float acc[10];
        #pragma unroll
        for (int c = 0; c < 10; ++c) acc[c] = 0.f;

        // L1: 4 row-pairs x 2 quad-cols, all thread-local.
        float a1[4][2];
        #pragma unroll
        for (int qr = 0; qr < 4; ++qr) {
            float4 u0 = *(const float4*)(xr + (size_t)(2 * qr)     * WW);
            float4 u1 = *(const float4*)(xr + (size_t)(2 * qr + 1) * WW);
            float h_[2], v_[2], d_[2];
            haar_fwd(u0.x, u0.y, u1.x, u1.y, a1[qr][0], h_[0], v_[0], d_[0]);
            haar_fwd(u0.z, u0.w, u1.z, u1.w, a1[qr][1], h_[1], v_[1], d_[1]);
            #pragma unroll
            for (int qc = 0; qc < 2; ++qc)
                #pragma unroll
                for (int c = 0; c < 3; ++c)
                    acc[7 + c] += h_[qc] * w1[0][qr][qc * 3 + c]
                                + v_[qc] * w1[1][qr][qc * 3 + c]
                                + d_[qc] * w1[2][qr][qc * 3 + c];
        }

        // L2: 2 quads, thread-local (a1 is 4 rows x 2 cols).
        float a2[2];
        #pragma unroll
        for (int QR = 0; QR < 2; ++QR) {
            float h2, v2, d2;
            haar_fwd(a1[2 * QR][0], a1[2 * QR][1], a1[2 * QR + 1][0], a1[2 * QR + 1][1],
                     a2[QR], h2, v2, d2);
            #pragma unroll
            for (int c = 0; c < 3; ++c)
                acc[4 + c] += h2 * w2[0][QR][c] + v2 * w2[1][QR][c] + d2 * w2[2][QR][c];
        }

        // L3: pair lanes t, t^1. Even lane accumulates.
        {
            float oa0 = __shfl_xor(a2[0], 1);
            float oa1 = __shfl_xor(a2[1], 1);
            if (!(t & 1)) {
                float a3, h3, v3, d3;
                haar_fwd(a2[0], oa0, a2[1], oa1, a3, h3, v3, d3);
                acc[0] += a3 * wa;
                #pragma unroll
                for (int c = 0; c < 3; ++c)
                    acc[1 + c] += h3 * w3[0][c] + v3 * w3[1][c] + d3 * w3[2][c];
            }
        }

        // Wave butterfly; lane 0 stores the 10-float partial row.
        #pragma unroll
        for (int c = 0; c < 10; ++c) {
            float s = acc[c];
            #pragma unroll
            for (int off = 1; off < 64; off <<= 1) s += __shfl_xor(s, off);
            acc[c] = s;
        }
        if (lane == 0) {
            float* row = partial + ((size_t)b * ROWS_PER_IMG + (size_t)strip * 4 + wave) * 10;
            #pragma unroll
            for (int c = 0; c < 10; ++c) row[c] = acc[c];
        }
    }
}

// ---------------------------------------------------------------------------
// Kernel 2: reduce 512 partial rows per image, biases, sigmoid/softmax.
// Grid: (B); 64 threads. gates: [0]=sigmoid approx, [1..3]=lvl3, [4..6]=lvl2,
// [7..9]=lvl1.
// ---------------------------------------------------------------------------
__global__ __launch_bounds__(64) void wa_gates(
    const float* __restrict__ partial,
    const float* __restrict__ ba,
    const float* __restrict__ bd1,
    const float* __restrict__ bd2,
    const float* __restrict__ bd3,
    float* __restrict__ gates)
{
    const int b = blockIdx.x;
    const int l = threadIdx.x;
    float v[10];
    #pragma unroll
    for (int c = 0; c < 10; ++c) v[c] = 0.f;
    for (int r = l; r < ROWS_PER_IMG; r += 64) {
        const float* row = partial + ((size_t)b * ROWS_PER_IMG + r) * 10;
        #pragma unroll
        for (int c = 0; c < 10; ++c) v[c] += row[c];
    }
    #pragma unroll
    for (int c = 0; c < 10; ++c) {
        #pragma unroll
        for (int off = 1; off < 64; off <<= 1) v[c] += __shfl_xor(v[c], off);
    }
    if (l == 0) {
        float* G = gates + b * 10;
        G[0] = 1.f / (1.f + expf(-(v[0] + ba[0])));
        const float* bds[3] = { bd1, bd2, bd3 };
        #pragma unroll
        for (int lv = 0; lv < 3; ++lv) {
            float l0 = v[1 + 3 * lv + 0] + bds[lv][0];
            float l1 = v[1 + 3 * lv + 1] + bds[lv][1];
            float l2 = v[1 + 3 * lv + 2] + bds[lv][2];
            float m = fmaxf(l0, fmaxf(l1, l2));
            float e0 = expf(l0 - m), e1 = expf(l1 - m), e2 = expf(l2 - m);
            float inv = 1.f / (e0 + e1 + e2);
            G[1 + 3 * lv + 0] = e0 * inv;
            G[1 + 3 * lv + 1] = e1 * inv;
            G[1 + 3 * lv + 2] = e2 * inv;
        }
    }
}

// ---------------------------------------------------------------------------
// Kernel 3: recompute coefficients, gate, inverse-DWT, write. Column-slab
// layout (thread = 4 cols x 8 rows): loads AND stores are full contiguous
// 1KB/wave lines; only one shuffle pair exchange (L3). Grid: (128, B).
// ---------------------------------------------------------------------------
__global__ __launch_bounds__(256) void wa_recon(
    const float* __restrict__ x,
    const float* __restrict__ gates,
    float* __restrict__ out)
{
    const int strip = blockIdx.x;
    const int b = blockIdx.y;
    const int t = threadIdx.x;

    __shared__ float g[10];
    if (t < 10) g[t] = gates[b * 10 + t];
    __syncthreads();

    const float* xr = x + (size_t)b * HH * WW + (size_t)strip * 8 * WW + 4 * t;

    // Forward: keep all detail coefficients.
    float a1[4][2], h1[4][2], v1[4][2], d1[4][2];
    #pragma unroll
    for (int qr = 0; qr < 4; ++qr) {
        float4 u0 = *(const float4*)(xr + (size_t)(2 * qr)     * WW);
        float4 u1 = *(const float4*)(xr + (size_t)(2 * qr + 1) * WW);
        haar_fwd(u0.x, u0.y, u1.x, u1.y, a1[qr][0], h1[qr][0], v1[qr][0], d1[qr][0]);
        haar_fwd(u0.z, u0.w, u1.z, u1.w, a1[qr][1], h1[qr][1], v1[qr][1], d1[qr][1]);
    }
    float a2[2], h2[2], v2[2], d2[2];
    #pragma unroll
    for (int QR = 0; QR < 2; ++QR)
        haar_fwd(a1[2 * QR][0], a1[2 * QR][1], a1[2 * QR + 1][0], a1[2 * QR + 1][1],
                 a2[QR], h2[QR], v2[QR], d2[QR]);

    // L3 redundantly on both pair lanes.
    float oa0 = __shfl_xor(a2[0], 1);
    float oa1 = __shfl_xor(a2[1], 1);
    const bool rightside = t & 1;
    float a3, h3, v3, d3;
    if (!rightside) haar_fwd(a2[0], oa0, a2[1], oa1, a3, h3, v3, d3);
    else            haar_fwd(oa0, a2[0], oa1, a2[1], a3, h3, v3, d3);

    // Gate + inverse.
    a3 *= g[0];
    float P, Q, R, S;
    haar_inv(a3, h3 * g[1], v3 * g[2], d3 * g[3], P, Q, R, S);
    float r2[2];
    r2[0] = rightside ? Q : P;        // L2-approx at (QR=0, my col)
    r2[1] = rightside ? S : R;        // (QR=1, my col)

    float ra1[4][2];
    #pragma unroll
    for (int QR = 0; QR < 2; ++QR) {
        haar_inv(r2[QR], h2[QR] * g[4], v2[QR] * g[5], d2[QR] * g[6], P, Q, R, S);
        ra1[2 * QR][0] = P; ra1[2 * QR][1] = Q;
        ra1[2 * QR + 1][0] = R; ra1[2 * QR + 1][1] = S;
    }

    float* orow = out + (size_t)b * HH * WW + (size_t)strip * 8 * WW + 4 * t;
    #pragma unroll
    for (int qr = 0; qr < 4; ++qr) {
        float4 o0, o1;
        haar_inv(ra1[qr][0], h1[qr][0] * g[7], v1[qr][0] * g[8], d1[qr][0] * g[9],
                 o0.x, o0.y, o1.x, o1.y);
        haar_inv(ra1[qr][1], h1[qr][1] * g[7], v1[qr][1] * g[8], d1[qr][1] * g[9],
                 o0.z, o0.w, o1.z, o1.w);
        *(float4*)(orow + (size_t)(2 * qr)     * WW) = o0;
        *(float4*)(orow + (size_t)(2 * qr + 1) * WW) = o1;
    }
}

extern "C" void kernel_launch(void* const* d_in, const int* in_sizes, int n_in,
                              void* d_out, int out_size, void* d_ws, size_t ws_size,
                              hipStream_t stream) {
    const float* x   = (const float*)d_in[0];
    const float* Wa  = (const float*)d_in[1];
    const float* ba  = (const float*)d_in[2];
    const float* Wd1 = (const float*)d_in[3];
    const float* bd1 = (const float*)d_in[4];
    const float* Wd2 = (const float*)d_in[5];
    const float* bd2 = (const float*)d_in[6];
    const float* Wd3 = (const float*)d_in[7];
    const float* bd3 = (const float*)d_in[8];
    float* out = (float*)d_out;

    const int B = in_sizes[0] / (HH * WW);

    float* partial = (float*)d_ws;                               // [B, 512, 10]
    float* gates   = partial + (size_t)B * ROWS_PER_IMG * 10;    // [B, 10]

    int nchunk = NCHUNK, ipc = B / NCHUNK;
    if (B % NCHUNK) { nchunk = B; ipc = 1; }   // safety for odd B

    dim3 fgrid(128, nchunk);
    wa_fwd_dots<<<fgrid, 256, 0, stream>>>(x, Wa, Wd1, Wd2, Wd3, partial, ipc);
    wa_gates<<<B, 64, 0, stream>>>(partial, ba, bd1, bd2, bd3, gates);
    dim3 rgrid(128, B);
    wa_recon<<<rgrid, 256, 0, stream>>>(x, gates, out);
}